// Round 5
// baseline (671.590 us; speedup 1.0000x reference)
//
#include <hip/hip_runtime.h>
#include <cstdint>
#include <cstddef>

typedef __bf16 bf16;
typedef __bf16 bf16x8 __attribute__((ext_vector_type(8)));
typedef __bf16 bf16x4 __attribute__((ext_vector_type(4)));
typedef float  f32x4  __attribute__((ext_vector_type(4)));

static constexpr int Bb = 4, Tt = 2048, Ee = 1024, Hh = 16, HDd = 64;
static constexpr int M1 = Bb * Tt;   // 8192
static constexpr int N1 = 3 * Ee;    // 3072
static constexpr int K1 = Ee;        // 1024

__device__ __forceinline__ f32x4 mfma16(bf16x8 a, bf16x8 b, f32x4 c) {
  return __builtin_amdgcn_mfma_f32_16x16x32_bf16(a, b, c, 0, 0, 0);
}

__device__ __forceinline__ void gl_lds16(bf16* lds, const bf16* g) {
  __builtin_amdgcn_global_load_lds(
      (const __attribute__((address_space(1))) void*)g,
      (__attribute__((address_space(3))) void*)lds, 16, 0, 0);
}

// ---------- cast fp32 -> bf16 (x4 vectorized) ----------
__global__ void k_cast(const float* __restrict__ in, bf16* __restrict__ out, int n4) {
  int i = blockIdx.x * blockDim.x + threadIdx.x;
  if (i >= n4) return;
  float4 v = reinterpret_cast<const float4*>(in)[i];
  bf16x4 o = { (bf16)v.x, (bf16)v.y, (bf16)v.z, (bf16)v.w };
  reinterpret_cast<bf16x4*>(out)[i] = o;
}

// ---------- transpose + cast: in[R][C] f32 -> out[C][R] bf16 ----------
__global__ void k_transpose_cast(const float* __restrict__ in, bf16* __restrict__ out,
                                 int R, int C) {
  __shared__ bf16 tile[32][33];
  int c0 = blockIdx.x * 32, r0 = blockIdx.y * 32;
  int tx = threadIdx.x & 31, ty = threadIdx.x >> 5;  // 256 thr: ty 0..7
#pragma unroll
  for (int i = 0; i < 32; i += 8)
    tile[ty + i][tx] = (bf16)in[(size_t)(r0 + ty + i) * C + c0 + tx];
  __syncthreads();
#pragma unroll
  for (int i = 0; i < 32; i += 8)
    out[(size_t)(c0 + ty + i) * R + r0 + tx] = tile[tx][ty + i];
}

// ---------- TN GEMM: C[M][N] = A[M][K] * Bt[N][K]^T  (+bias) ----------
// EPI 0: fp32 out[M][N] = acc + bias
// EPI 1: qkv scatter: q (scaled 1/8), k as [BH][T][64], v transposed [BH][64][T]
template <int EPI>
__global__ __launch_bounds__(256, 2)
void k_gemm_tn(const bf16* __restrict__ A, const bf16* __restrict__ Bt,
               const float* __restrict__ bias, float* __restrict__ outf,
               bf16* __restrict__ qo, bf16* __restrict__ ko, bf16* __restrict__ vto,
               int M, int N, int K) {
  __shared__ bf16 As[128 * 32];
  __shared__ bf16 Bs[128 * 32];
  const int n0 = blockIdx.x * 128;
  const int m0 = blockIdx.y * 128;
  const int w = threadIdx.x >> 6, lane = threadIdx.x & 63;
  const int wr = w >> 1, wc = w & 1;
  const int lr = lane & 15, lh = lane >> 4;

  // staging source: chunk of 16 rows; lane -> row lane/4, k-offset (lane&3)*8
  const int srow = lane >> 2;
  const int skk = (lane & 3) * 8;

  const bf16* gA0 = A + (size_t)(m0 + 32 * w + srow) * K + skk;
  const bf16* gA1 = A + (size_t)(m0 + 32 * w + 16 + srow) * K + skk;
  const bf16* gB0 = Bt + (size_t)(n0 + 32 * w + srow) * K + skk;
  const bf16* gB1 = Bt + (size_t)(n0 + 32 * w + 16 + srow) * K + skk;
  bf16* lA0 = As + (2 * w) * 512;
  bf16* lA1 = As + (2 * w + 1) * 512;
  bf16* lB0 = Bs + (2 * w) * 512;
  bf16* lB1 = Bs + (2 * w + 1) * 512;

  f32x4 acc[4][4] = {};

  for (int k0 = 0; k0 < K; k0 += 32) {
    gl_lds16(lA0, gA0 + k0);
    gl_lds16(lA1, gA1 + k0);
    gl_lds16(lB0, gB0 + k0);
    gl_lds16(lB1, gB1 + k0);
    __syncthreads();
    bf16x8 af[4], bfr[4];
#pragma unroll
    for (int m = 0; m < 4; ++m)
      af[m] = *reinterpret_cast<const bf16x8*>(As + (wr * 64 + m * 16 + lr) * 32 + lh * 8);
#pragma unroll
    for (int n = 0; n < 4; ++n)
      bfr[n] = *reinterpret_cast<const bf16x8*>(Bs + (wc * 64 + n * 16 + lr) * 32 + lh * 8);
#pragma unroll
    for (int m = 0; m < 4; ++m)
#pragma unroll
      for (int n = 0; n < 4; ++n)
        acc[m][n] = mfma16(af[m], bfr[n], acc[m][n]);
    __syncthreads();
  }

#pragma unroll
  for (int mf = 0; mf < 4; ++mf) {
#pragma unroll
    for (int nf = 0; nf < 4; ++nf) {
      int gn = n0 + wc * 64 + nf * 16 + lr;
      float bv = bias[gn];
#pragma unroll
      for (int r = 0; r < 4; ++r) {
        int gm = m0 + wr * 64 + mf * 16 + lh * 4 + r;
        float v = acc[mf][nf][r] + bv;
        if (EPI == 0) {
          outf[(size_t)gm * N + gn] = v;
        } else {
          int b = gm >> 11, t = gm & (Tt - 1);
          int sec = gn >> 10, rem = gn & (Ee - 1);
          int h = rem >> 6, d = rem & 63;
          size_t bh = (size_t)(b * Hh + h);
          if (sec == 0)
            qo[(bh * Tt + t) * HDd + d] = (bf16)(v * 0.125f);  // fold 1/sqrt(64)
          else if (sec == 1)
            ko[(bh * Tt + t) * HDd + d] = (bf16)v;
          else
            vto[(bh * HDd + d) * Tt + t] = (bf16)v;
        }
      }
    }
  }
}

// ---------- flash attention: Q[BH][T][64] x K[BH][T][64] -> causal softmax -> *Vt[BH][64][T] ----------
// block = 4 waves, 64 Q rows (16/wave); KV tiles of 64
__global__ __launch_bounds__(256, 2)
void k_attn(const bf16* __restrict__ Q, const bf16* __restrict__ Kg,
            const bf16* __restrict__ Vt, bf16* __restrict__ Y) {
  __shared__ bf16 P[4][16][72];  // per-wave P tile, row stride 144B (16B aligned)
  const int blk = blockIdx.x;
  const int bh = blk >> 5, qb = blk & 31;
  const int w = threadIdx.x >> 6, lane = threadIdx.x & 63;
  const int lr = lane & 15, lh = lane >> 4;
  const int q0 = qb * 64 + w * 16;

  const bf16* qp = Q + ((size_t)bh * Tt + q0 + lr) * HDd + lh * 8;
  bf16x8 aq0 = *reinterpret_cast<const bf16x8*>(qp);
  bf16x8 aq1 = *reinterpret_cast<const bf16x8*>(qp + 32);

  float mrow[4], lrow[4];
  f32x4 o[4] = {};
#pragma unroll
  for (int r = 0; r < 4; ++r) { mrow[r] = -INFINITY; lrow[r] = 0.f; }

  const bf16* kb = Kg + (size_t)bh * Tt * HDd;
  const bf16* vb = Vt + (size_t)bh * HDd * Tt;

  for (int t = 0; t <= qb; ++t) {
    const int kv0 = t * 64;
    f32x4 s[4] = {};
#pragma unroll
    for (int fc = 0; fc < 4; ++fc) {
      const bf16* kp = kb + (size_t)(kv0 + fc * 16 + lr) * HDd + lh * 8;
      bf16x8 b0 = *reinterpret_cast<const bf16x8*>(kp);
      bf16x8 b1 = *reinterpret_cast<const bf16x8*>(kp + 32);
      s[fc] = mfma16(aq0, b0, s[fc]);
      s[fc] = mfma16(aq1, b1, s[fc]);
    }
    if (t == qb) {  // diagonal tile: causal mask
#pragma unroll
      for (int fc = 0; fc < 4; ++fc)
#pragma unroll
        for (int r = 0; r < 4; ++r)
          if (kv0 + fc * 16 + lr > q0 + lh * 4 + r) s[fc][r] = -INFINITY;
    }
    float pm[4], al[4], ps[4];
#pragma unroll
    for (int r = 0; r < 4; ++r)
      pm[r] = fmaxf(fmaxf(s[0][r], s[1][r]), fmaxf(s[2][r], s[3][r]));
#pragma unroll
    for (int msk = 1; msk < 16; msk <<= 1)
#pragma unroll
      for (int r = 0; r < 4; ++r)
        pm[r] = fmaxf(pm[r], __shfl_xor(pm[r], msk));
#pragma unroll
    for (int r = 0; r < 4; ++r) {
      float nm = fmaxf(mrow[r], pm[r]);
      al[r] = __expf(mrow[r] - nm);
      mrow[r] = nm;
      ps[r] = 0.f;
    }
#pragma unroll
    for (int fc = 0; fc < 4; ++fc) {
#pragma unroll
      for (int r = 0; r < 4; ++r) {
        float p = __expf(s[fc][r] - mrow[r]);
        ps[r] += p;
        P[w][lh * 4 + r][fc * 16 + lr] = (bf16)p;
      }
    }
#pragma unroll
    for (int msk = 1; msk < 16; msk <<= 1)
#pragma unroll
      for (int r = 0; r < 4; ++r)
        ps[r] += __shfl_xor(ps[r], msk);
#pragma unroll
    for (int r = 0; r < 4; ++r)
      lrow[r] = lrow[r] * al[r] + ps[r];
#pragma unroll
    for (int df = 0; df < 4; ++df)
#pragma unroll
      for (int r = 0; r < 4; ++r)
        o[df][r] *= al[r];
    __syncthreads();  // P writes visible (cross-lane) before transposed reads
    bf16x8 pa0 = *reinterpret_cast<const bf16x8*>(&P[w][lr][lh * 8]);
    bf16x8 pa1 = *reinterpret_cast<const bf16x8*>(&P[w][lr][32 + lh * 8]);
#pragma unroll
    for (int df = 0; df < 4; ++df) {
      const bf16* vp = vb + (size_t)(df * 16 + lr) * Tt + kv0 + lh * 8;
      bf16x8 v0 = *reinterpret_cast<const bf16x8*>(vp);
      bf16x8 v1 = *reinterpret_cast<const bf16x8*>(vp + 32);
      o[df] = mfma16(pa0, v0, o[df]);
      o[df] = mfma16(pa1, v1, o[df]);
    }
  }

  const int b = bh >> 4, h = bh & 15;
#pragma unroll
  for (int df = 0; df < 4; ++df) {
#pragma unroll
    for (int r = 0; r < 4; ++r) {
      int qrow = q0 + lh * 4 + r;
      float v = o[df][r] / lrow[r];
      Y[((size_t)b * Tt + qrow) * Ee + h * HDd + df * 16 + lr] = (bf16)v;
    }
  }
}

extern "C" void kernel_launch(void* const* d_in, const int* in_sizes, int n_in,
                              void* d_out, int out_size, void* d_ws, size_t ws_size,
                              hipStream_t stream) {
  const float* x = (const float*)d_in[0];
  const float* w_attn = (const float*)d_in[1];
  const float* b_attn = (const float*)d_in[2];
  const float* w_proj = (const float*)d_in[3];
  const float* b_proj = (const float*)d_in[4];

  char* ws = (char*)d_ws;
  bf16* xbf = (bf16*)ws;                        // 16,777,216 B (later reused as Y)
  bf16* wat = (bf16*)(ws + 16777216);           //  6,291,456 B  w_attn^T bf16
  bf16* wpt = (bf16*)(ws + 23068672);           //  2,097,152 B  w_proj^T bf16
  bf16* vt  = (bf16*)(ws + 25165824);           // 16,777,216 B  V^T
  bf16* q   = (bf16*)d_out;                     // scratch in d_out (16.8 MB)
  bf16* k   = q + (size_t)M1 * Ee;              // scratch in d_out (16.8 MB)
  bf16* y   = xbf;                              // alias: x_bf16 dead after GEMM1

  // 1) casts / transposes
  k_cast<<<dim3((M1 * Ee / 4 + 255) / 256), dim3(256), 0, stream>>>(x, xbf, M1 * Ee / 4);
  k_transpose_cast<<<dim3(N1 / 32, K1 / 32), dim3(256), 0, stream>>>(w_attn, wat, K1, N1);
  k_transpose_cast<<<dim3(Ee / 32, Ee / 32), dim3(256), 0, stream>>>(w_proj, wpt, Ee, Ee);

  // 2) QKV GEMM (scatter epilogue)
  k_gemm_tn<1><<<dim3(N1 / 128, M1 / 128), dim3(256), 0, stream>>>(
      xbf, wat, b_attn, nullptr, q, k, vt, M1, N1, K1);

  // 3) flash attention
  k_attn<<<dim3(Bb * Hh * (Tt / 64)), dim3(256), 0, stream>>>(q, k, vt, y);

  // 4) output projection (fp32 out)
  k_gemm_tn<0><<<dim3(Ee / 128, M1 / 128), dim3(256), 0, stream>>>(
      y, wpt, b_proj, (float*)d_out, nullptr, nullptr, nullptr, M1, Ee, K1);
}

// Round 8
// 535.383 us; speedup vs baseline: 1.2544x; 1.2544x over previous
//
#include <hip/hip_runtime.h>
#include <cstdint>
#include <cstddef>

typedef __bf16 bf16;
typedef __bf16 bf16x8 __attribute__((ext_vector_type(8)));
typedef __bf16 bf16x4 __attribute__((ext_vector_type(4)));
typedef float  f32x4  __attribute__((ext_vector_type(4)));

static constexpr int Bb = 4, Tt = 2048, Ee = 1024, Hh = 16, HDd = 64;
static constexpr int M1 = Bb * Tt;   // 8192
static constexpr int N1 = 3 * Ee;    // 3072
static constexpr int K1 = Ee;        // 1024

__device__ __forceinline__ f32x4 mfma16(bf16x8 a, bf16x8 b, f32x4 c) {
  return __builtin_amdgcn_mfma_f32_16x16x32_bf16(a, b, c, 0, 0, 0);
}

__device__ __forceinline__ void gl_lds16(bf16* lds, const bf16* g) {
  __builtin_amdgcn_global_load_lds(
      (const __attribute__((address_space(1))) void*)g,
      (__attribute__((address_space(3))) void*)lds, 16, 0, 0);
}

// ---------- cast fp32 -> bf16 (x4 vectorized) ----------
__global__ void k_cast(const float* __restrict__ in, bf16* __restrict__ out, int n4) {
  int i = blockIdx.x * blockDim.x + threadIdx.x;
  if (i >= n4) return;
  float4 v = reinterpret_cast<const float4*>(in)[i];
  bf16x4 o = { (bf16)v.x, (bf16)v.y, (bf16)v.z, (bf16)v.w };
  reinterpret_cast<bf16x4*>(out)[i] = o;
}

// ---------- transpose + cast: in[R][C] f32 -> out[C][R] bf16 ----------
__global__ void k_transpose_cast(const float* __restrict__ in, bf16* __restrict__ out,
                                 int R, int C) {
  __shared__ bf16 tile[32][33];
  int c0 = blockIdx.x * 32, r0 = blockIdx.y * 32;
  int tx = threadIdx.x & 31, ty = threadIdx.x >> 5;  // 256 thr: ty 0..7
#pragma unroll
  for (int i = 0; i < 32; i += 8)
    tile[ty + i][tx] = (bf16)in[(size_t)(r0 + ty + i) * C + c0 + tx];
  __syncthreads();
#pragma unroll
  for (int i = 0; i < 32; i += 8)
    out[(size_t)(c0 + ty + i) * R + r0 + tx] = tile[tx][ty + i];
}

// ---------- TN GEMM: C[M][N] = A[M][K] * Bt[N][K]^T  (+bias) ----------
// EPI 0: fp32 out[M][N] = acc + bias
// EPI 1: qkv scatter: q (scaled 1/8), k as [BH][T][64], v transposed [BH][64][T]
template <int EPI>
__global__ __launch_bounds__(256, 2)
void k_gemm_tn(const bf16* __restrict__ A, const bf16* __restrict__ Bt,
               const float* __restrict__ bias, float* __restrict__ outf,
               bf16* __restrict__ qo, bf16* __restrict__ ko, bf16* __restrict__ vto,
               int M, int N, int K) {
  __shared__ bf16 As[128 * 32];
  __shared__ bf16 Bs[128 * 32];
  const int n0 = blockIdx.x * 128;
  const int m0 = blockIdx.y * 128;
  const int w = threadIdx.x >> 6, lane = threadIdx.x & 63;
  const int wr = w >> 1, wc = w & 1;
  const int lr = lane & 15, lh = lane >> 4;

  // staging source: chunk of 16 rows; lane -> row lane/4, k-offset (lane&3)*8
  const int srow = lane >> 2;
  const int skk = (lane & 3) * 8;

  const bf16* gA0 = A + (size_t)(m0 + 32 * w + srow) * K + skk;
  const bf16* gA1 = A + (size_t)(m0 + 32 * w + 16 + srow) * K + skk;
  const bf16* gB0 = Bt + (size_t)(n0 + 32 * w + srow) * K + skk;
  const bf16* gB1 = Bt + (size_t)(n0 + 32 * w + 16 + srow) * K + skk;
  bf16* lA0 = As + (2 * w) * 512;
  bf16* lA1 = As + (2 * w + 1) * 512;
  bf16* lB0 = Bs + (2 * w) * 512;
  bf16* lB1 = Bs + (2 * w + 1) * 512;

  f32x4 acc[4][4] = {};

  for (int k0 = 0; k0 < K; k0 += 32) {
    gl_lds16(lA0, gA0 + k0);
    gl_lds16(lA1, gA1 + k0);
    gl_lds16(lB0, gB0 + k0);
    gl_lds16(lB1, gB1 + k0);
    __syncthreads();
    bf16x8 af[4], bfr[4];
#pragma unroll
    for (int m = 0; m < 4; ++m)
      af[m] = *reinterpret_cast<const bf16x8*>(As + (wr * 64 + m * 16 + lr) * 32 + lh * 8);
#pragma unroll
    for (int n = 0; n < 4; ++n)
      bfr[n] = *reinterpret_cast<const bf16x8*>(Bs + (wc * 64 + n * 16 + lr) * 32 + lh * 8);
#pragma unroll
    for (int m = 0; m < 4; ++m)
#pragma unroll
      for (int n = 0; n < 4; ++n)
        acc[m][n] = mfma16(af[m], bfr[n], acc[m][n]);
    __syncthreads();
  }

#pragma unroll
  for (int mf = 0; mf < 4; ++mf) {
#pragma unroll
    for (int nf = 0; nf < 4; ++nf) {
      int gn = n0 + wc * 64 + nf * 16 + lr;
      float bv = bias[gn];
#pragma unroll
      for (int r = 0; r < 4; ++r) {
        int gm = m0 + wr * 64 + mf * 16 + lh * 4 + r;
        float v = acc[mf][nf][r] + bv;
        if (EPI == 0) {
          outf[(size_t)gm * N + gn] = v;
        } else {
          int b = gm >> 11, t = gm & (Tt - 1);
          int sec = gn >> 10, rem = gn & (Ee - 1);
          int h = rem >> 6, d = rem & 63;
          size_t bh = (size_t)(b * Hh + h);
          if (sec == 0)
            qo[(bh * Tt + t) * HDd + d] = (bf16)(v * 0.125f);  // fold 1/sqrt(64)
          else if (sec == 1)
            ko[(bh * Tt + t) * HDd + d] = (bf16)v;
          else
            vto[(bh * HDd + d) * Tt + t] = (bf16)v;
        }
      }
    }
  }
}

// ---------- flash attention: Q[BH][T][64] x K[BH][T][64] -> causal softmax -> *Vt[BH][64][T] ----------
// block = 4 independent waves, 64 Q rows (16/wave); KV tiles of 64.
// XCD-remap: each XCD owns 8 contiguous heads -> per-XCD K/V working set = 4 MB ~= L2.
__global__ __launch_bounds__(256, 2)
void k_attn(const bf16* __restrict__ Q, const bf16* __restrict__ Kg,
            const bf16* __restrict__ Vt, bf16* __restrict__ Y) {
  __shared__ bf16 P[4][16][72];  // per-wave P tile, row stride 144B (16B aligned)
  const int blk = blockIdx.x;
  // bijective XCD-contiguous remap (2048 blocks, 8 XCDs, XCD = blk%8):
  const int work = ((blk & 7) << 8) + (blk >> 3);
  const int bh = work >> 5, qb = work & 31;
  const int w = threadIdx.x >> 6, lane = threadIdx.x & 63;
  const int lr = lane & 15, lh = lane >> 4;
  const int q0 = qb * 64 + w * 16;

  const bf16* qp = Q + ((size_t)bh * Tt + q0 + lr) * HDd + lh * 8;
  bf16x8 aq0 = *reinterpret_cast<const bf16x8*>(qp);
  bf16x8 aq1 = *reinterpret_cast<const bf16x8*>(qp + 32);

  float mrow[4], lrow[4];
  f32x4 o[4] = {};
#pragma unroll
  for (int r = 0; r < 4; ++r) { mrow[r] = -INFINITY; lrow[r] = 0.f; }

  const bf16* kb = Kg + (size_t)bh * Tt * HDd;
  const bf16* vb = Vt + (size_t)bh * HDd * Tt;

  for (int t = 0; t <= qb; ++t) {
    const int kv0 = t * 64;
    f32x4 s[4] = {};
#pragma unroll
    for (int fc = 0; fc < 4; ++fc) {
      const bf16* kp = kb + (size_t)(kv0 + fc * 16 + lr) * HDd + lh * 8;
      bf16x8 b0 = *reinterpret_cast<const bf16x8*>(kp);
      bf16x8 b1 = *reinterpret_cast<const bf16x8*>(kp + 32);
      s[fc] = mfma16(aq0, b0, s[fc]);
      s[fc] = mfma16(aq1, b1, s[fc]);
    }
    if (t == qb) {  // diagonal tile: causal mask
#pragma unroll
      for (int fc = 0; fc < 4; ++fc)
#pragma unroll
        for (int r = 0; r < 4; ++r)
          if (kv0 + fc * 16 + lr > q0 + lh * 4 + r) s[fc][r] = -INFINITY;
    }
    float pm[4], al[4], ps[4];
#pragma unroll
    for (int r = 0; r < 4; ++r)
      pm[r] = fmaxf(fmaxf(s[0][r], s[1][r]), fmaxf(s[2][r], s[3][r]));
#pragma unroll
    for (int msk = 1; msk < 16; msk <<= 1)
#pragma unroll
      for (int r = 0; r < 4; ++r)
        pm[r] = fmaxf(pm[r], __shfl_xor(pm[r], msk));
#pragma unroll
    for (int r = 0; r < 4; ++r) {
      float nm = fmaxf(mrow[r], pm[r]);
      al[r] = __expf(mrow[r] - nm);
      mrow[r] = nm;
      ps[r] = 0.f;
    }
#pragma unroll
    for (int fc = 0; fc < 4; ++fc) {
#pragma unroll
      for (int r = 0; r < 4; ++r) {
        float p = __expf(s[fc][r] - mrow[r]);
        ps[r] += p;
        P[w][lh * 4 + r][fc * 16 + lr] = (bf16)p;
      }
    }
#pragma unroll
    for (int msk = 1; msk < 16; msk <<= 1)
#pragma unroll
      for (int r = 0; r < 4; ++r)
        ps[r] += __shfl_xor(ps[r], msk);
#pragma unroll
    for (int r = 0; r < 4; ++r)
      lrow[r] = lrow[r] * al[r] + ps[r];
#pragma unroll
    for (int df = 0; df < 4; ++df)
#pragma unroll
      for (int r = 0; r < 4; ++r)
        o[df][r] *= al[r];
    // No __syncthreads: P is strictly per-wave; the compiler's lgkmcnt wait on
    // the LDS dependency (same-address alias exists per-lane) orders write->read.
    bf16x8 pa0 = *reinterpret_cast<const bf16x8*>(&P[w][lr][lh * 8]);
    bf16x8 pa1 = *reinterpret_cast<const bf16x8*>(&P[w][lr][32 + lh * 8]);
#pragma unroll
    for (int df = 0; df < 4; ++df) {
      const bf16* vp = vb + (size_t)(df * 16 + lr) * Tt + kv0 + lh * 8;
      bf16x8 v0 = *reinterpret_cast<const bf16x8*>(vp);
      bf16x8 v1 = *reinterpret_cast<const bf16x8*>(vp + 32);
      o[df] = mfma16(pa0, v0, o[df]);
      o[df] = mfma16(pa1, v1, o[df]);
    }
  }

  const int b = bh >> 4, h = bh & 15;
#pragma unroll
  for (int df = 0; df < 4; ++df) {
#pragma unroll
    for (int r = 0; r < 4; ++r) {
      int qrow = q0 + lh * 4 + r;
      float v = o[df][r] / lrow[r];
      Y[((size_t)b * Tt + qrow) * Ee + h * HDd + df * 16 + lr] = (bf16)v;
    }
  }
}

extern "C" void kernel_launch(void* const* d_in, const int* in_sizes, int n_in,
                              void* d_out, int out_size, void* d_ws, size_t ws_size,
                              hipStream_t stream) {
  const float* x = (const float*)d_in[0];
  const float* w_attn = (const float*)d_in[1];
  const float* b_attn = (const float*)d_in[2];
  const float* w_proj = (const float*)d_in[3];
  const float* b_proj = (const float*)d_in[4];

  char* ws = (char*)d_ws;
  bf16* xbf = (bf16*)ws;                        // 16,777,216 B (later reused as Y)
  bf16* wat = (bf16*)(ws + 16777216);           //  6,291,456 B  w_attn^T bf16
  bf16* wpt = (bf16*)(ws + 23068672);           //  2,097,152 B  w_proj^T bf16
  bf16* vt  = (bf16*)(ws + 25165824);           // 16,777,216 B  V^T
  bf16* q   = (bf16*)d_out;                     // scratch in d_out (16.8 MB)
  bf16* k   = q + (size_t)M1 * Ee;              // scratch in d_out (16.8 MB)
  bf16* y   = xbf;                              // alias: x_bf16 dead after GEMM1

  // 1) casts / transposes
  k_cast<<<dim3((M1 * Ee / 4 + 255) / 256), dim3(256), 0, stream>>>(x, xbf, M1 * Ee / 4);
  k_transpose_cast<<<dim3(N1 / 32, K1 / 32), dim3(256), 0, stream>>>(w_attn, wat, K1, N1);
  k_transpose_cast<<<dim3(Ee / 32, Ee / 32), dim3(256), 0, stream>>>(w_proj, wpt, Ee, Ee);

  // 2) QKV GEMM (scatter epilogue)
  k_gemm_tn<1><<<dim3(N1 / 128, M1 / 128), dim3(256), 0, stream>>>(
      xbf, wat, b_attn, nullptr, q, k, vt, M1, N1, K1);

  // 3) flash attention
  k_attn<<<dim3(Bb * Hh * (Tt / 64)), dim3(256), 0, stream>>>(q, k, vt, y);

  // 4) output projection (fp32 out)
  k_gemm_tn<0><<<dim3(Ee / 128, M1 / 128), dim3(256), 0, stream>>>(
      y, wpt, b_proj, (float*)d_out, nullptr, nullptr, nullptr, M1, Ee, K1);
}

// Round 9
// 451.249 us; speedup vs baseline: 1.4883x; 1.1864x over previous
//
#include <hip/hip_runtime.h>
#include <cstdint>
#include <cstddef>

typedef __bf16 bf16;
typedef __bf16 bf16x8 __attribute__((ext_vector_type(8)));
typedef __bf16 bf16x4 __attribute__((ext_vector_type(4)));
typedef float  f32x4  __attribute__((ext_vector_type(4)));

static constexpr int Bb = 4, Tt = 2048, Ee = 1024, Hh = 16, HDd = 64;
static constexpr int M1 = Bb * Tt;   // 8192
static constexpr int N1 = 3 * Ee;    // 3072
static constexpr int K1 = Ee;        // 1024

__device__ __forceinline__ f32x4 mfma16(bf16x8 a, bf16x8 b, f32x4 c) {
  return __builtin_amdgcn_mfma_f32_16x16x32_bf16(a, b, c, 0, 0, 0);
}

__device__ __forceinline__ void gl_lds16(bf16* lds, const bf16* g) {
  __builtin_amdgcn_global_load_lds(
      (const __attribute__((address_space(1))) void*)g,
      (__attribute__((address_space(3))) void*)lds, 16, 0, 0);
}

// ---------- cast fp32 -> bf16 (x4 vectorized) ----------
__global__ void k_cast(const float* __restrict__ in, bf16* __restrict__ out, int n4) {
  int i = blockIdx.x * blockDim.x + threadIdx.x;
  if (i >= n4) return;
  float4 v = reinterpret_cast<const float4*>(in)[i];
  bf16x4 o = { (bf16)v.x, (bf16)v.y, (bf16)v.z, (bf16)v.w };
  reinterpret_cast<bf16x4*>(out)[i] = o;
}

// ---------- transpose + cast: in[R][C] f32 -> out[C][R] bf16 ----------
__global__ void k_transpose_cast(const float* __restrict__ in, bf16* __restrict__ out,
                                 int R, int C) {
  __shared__ bf16 tile[32][33];
  int c0 = blockIdx.x * 32, r0 = blockIdx.y * 32;
  int tx = threadIdx.x & 31, ty = threadIdx.x >> 5;  // 256 thr: ty 0..7
#pragma unroll
  for (int i = 0; i < 32; i += 8)
    tile[ty + i][tx] = (bf16)in[(size_t)(r0 + ty + i) * C + c0 + tx];
  __syncthreads();
#pragma unroll
  for (int i = 0; i < 32; i += 8)
    out[(size_t)(c0 + ty + i) * R + r0 + tx] = tile[tx][ty + i];
}

// ---------- TN GEMM: C[M][N] = A[M][K] * Bt[N][K]^T  (+bias) ----------
// EPI 0: fp32 out[M][N] = acc + bias
// EPI 1: qkv scatter: q (scaled 1/8), k as [BH][T][64], v transposed [BH][64][T]
template <int EPI>
__global__ __launch_bounds__(256, 2)
void k_gemm_tn(const bf16* __restrict__ A, const bf16* __restrict__ Bt,
               const float* __restrict__ bias, float* __restrict__ outf,
               bf16* __restrict__ qo, bf16* __restrict__ ko, bf16* __restrict__ vto,
               int M, int N, int K) {
  __shared__ bf16 As[128 * 32];
  __shared__ bf16 Bs[128 * 32];
  const int n0 = blockIdx.x * 128;
  const int m0 = blockIdx.y * 128;
  const int w = threadIdx.x >> 6, lane = threadIdx.x & 63;
  const int wr = w >> 1, wc = w & 1;
  const int lr = lane & 15, lh = lane >> 4;

  // staging source: chunk of 16 rows; lane -> row lane/4, k-offset (lane&3)*8
  const int srow = lane >> 2;
  const int skk = (lane & 3) * 8;

  const bf16* gA0 = A + (size_t)(m0 + 32 * w + srow) * K + skk;
  const bf16* gA1 = A + (size_t)(m0 + 32 * w + 16 + srow) * K + skk;
  const bf16* gB0 = Bt + (size_t)(n0 + 32 * w + srow) * K + skk;
  const bf16* gB1 = Bt + (size_t)(n0 + 32 * w + 16 + srow) * K + skk;
  bf16* lA0 = As + (2 * w) * 512;
  bf16* lA1 = As + (2 * w + 1) * 512;
  bf16* lB0 = Bs + (2 * w) * 512;
  bf16* lB1 = Bs + (2 * w + 1) * 512;

  f32x4 acc[4][4] = {};

  for (int k0 = 0; k0 < K; k0 += 32) {
    gl_lds16(lA0, gA0 + k0);
    gl_lds16(lA1, gA1 + k0);
    gl_lds16(lB0, gB0 + k0);
    gl_lds16(lB1, gB1 + k0);
    __syncthreads();
    bf16x8 af[4], bfr[4];
#pragma unroll
    for (int m = 0; m < 4; ++m)
      af[m] = *reinterpret_cast<const bf16x8*>(As + (wr * 64 + m * 16 + lr) * 32 + lh * 8);
#pragma unroll
    for (int n = 0; n < 4; ++n)
      bfr[n] = *reinterpret_cast<const bf16x8*>(Bs + (wc * 64 + n * 16 + lr) * 32 + lh * 8);
#pragma unroll
    for (int m = 0; m < 4; ++m)
#pragma unroll
      for (int n = 0; n < 4; ++n)
        acc[m][n] = mfma16(af[m], bfr[n], acc[m][n]);
    __syncthreads();
  }

#pragma unroll
  for (int mf = 0; mf < 4; ++mf) {
#pragma unroll
    for (int nf = 0; nf < 4; ++nf) {
      int gn = n0 + wc * 64 + nf * 16 + lr;
      float bv = bias[gn];
#pragma unroll
      for (int r = 0; r < 4; ++r) {
        int gm = m0 + wr * 64 + mf * 16 + lh * 4 + r;
        float v = acc[mf][nf][r] + bv;
        if (EPI == 0) {
          outf[(size_t)gm * N + gn] = v;
        } else {
          int b = gm >> 11, t = gm & (Tt - 1);
          int sec = gn >> 10, rem = gn & (Ee - 1);
          int h = rem >> 6, d = rem & 63;
          size_t bh = (size_t)(b * Hh + h);
          if (sec == 0)
            qo[(bh * Tt + t) * HDd + d] = (bf16)(v * 0.125f);  // fold 1/sqrt(64)
          else if (sec == 1)
            ko[(bh * Tt + t) * HDd + d] = (bf16)v;
          else
            vto[(bh * HDd + d) * Tt + t] = (bf16)v;
        }
      }
    }
  }
}

// ---------- flash attention: Q[BH][T][64] x K[BH][T][64] -> causal softmax -> *Vt[BH][64][T] ----------
// Pair-balanced schedule: 1024 blocks = 64 bh x 16 pairs; block handles Q-tiles
// qb_hi=31-pr then qb_lo=pr -> every block runs exactly 33 KV-tile iterations.
// XCD-remap: 128 consecutive works per XCD -> 8 heads/XCD -> K/V set ~4MB ~= L2.
__global__ __launch_bounds__(256, 2)
void k_attn(const bf16* __restrict__ Q, const bf16* __restrict__ Kg,
            const bf16* __restrict__ Vt, bf16* __restrict__ Y) {
  __shared__ bf16 P[4][16][72];  // per-wave P tile, row stride 144B (16B aligned)
  const int blk = blockIdx.x;
  // bijective XCD-contiguous remap (1024 blocks, 8 XCDs, XCD = blk%8):
  const int work = ((blk & 7) << 7) + (blk >> 3);
  const int bh = work >> 4, pr = work & 15;
  const int w = threadIdx.x >> 6, lane = threadIdx.x & 63;
  const int lr = lane & 15, lh = lane >> 4;

  const bf16* kb = Kg + (size_t)bh * Tt * HDd;
  const bf16* vb = Vt + (size_t)bh * HDd * Tt;
  const int b = bh >> 4, h = bh & 15;

  for (int ph = 0; ph < 2; ++ph) {
    const int qb = ph ? pr : (31 - pr);  // hi first: lo's K/V tiles then L2-warm
    const int q0 = qb * 64 + w * 16;

    const bf16* qp = Q + ((size_t)bh * Tt + q0 + lr) * HDd + lh * 8;
    bf16x8 aq0 = *reinterpret_cast<const bf16x8*>(qp);
    bf16x8 aq1 = *reinterpret_cast<const bf16x8*>(qp + 32);

    float mrow[4], lrow[4];
    f32x4 o[4] = {};
#pragma unroll
    for (int r = 0; r < 4; ++r) { mrow[r] = -INFINITY; lrow[r] = 0.f; }

    for (int t = 0; t <= qb; ++t) {
      const int kv0 = t * 64;
      f32x4 s[4] = {};
#pragma unroll
      for (int fc = 0; fc < 4; ++fc) {
        const bf16* kp = kb + (size_t)(kv0 + fc * 16 + lr) * HDd + lh * 8;
        bf16x8 b0 = *reinterpret_cast<const bf16x8*>(kp);
        bf16x8 b1 = *reinterpret_cast<const bf16x8*>(kp + 32);
        s[fc] = mfma16(aq0, b0, s[fc]);
        s[fc] = mfma16(aq1, b1, s[fc]);
      }
      if (t == qb) {  // diagonal tile: causal mask
#pragma unroll
        for (int fc = 0; fc < 4; ++fc)
#pragma unroll
          for (int r = 0; r < 4; ++r)
            if (kv0 + fc * 16 + lr > q0 + lh * 4 + r) s[fc][r] = -INFINITY;
      }
      float pm[4], al[4], ps[4];
#pragma unroll
      for (int r = 0; r < 4; ++r)
        pm[r] = fmaxf(fmaxf(s[0][r], s[1][r]), fmaxf(s[2][r], s[3][r]));
#pragma unroll
      for (int msk = 1; msk < 16; msk <<= 1)
#pragma unroll
        for (int r = 0; r < 4; ++r)
          pm[r] = fmaxf(pm[r], __shfl_xor(pm[r], msk));
#pragma unroll
      for (int r = 0; r < 4; ++r) {
        float nm = fmaxf(mrow[r], pm[r]);
        al[r] = __expf(mrow[r] - nm);
        mrow[r] = nm;
        ps[r] = 0.f;
      }
#pragma unroll
      for (int fc = 0; fc < 4; ++fc) {
#pragma unroll
        for (int r = 0; r < 4; ++r) {
          float p = __expf(s[fc][r] - mrow[r]);
          ps[r] += p;
          P[w][lh * 4 + r][fc * 16 + lr] = (bf16)p;
        }
      }
#pragma unroll
      for (int msk = 1; msk < 16; msk <<= 1)
#pragma unroll
        for (int r = 0; r < 4; ++r)
          ps[r] += __shfl_xor(ps[r], msk);
#pragma unroll
      for (int r = 0; r < 4; ++r)
        lrow[r] = lrow[r] * al[r] + ps[r];
#pragma unroll
      for (int df = 0; df < 4; ++df)
#pragma unroll
        for (int r = 0; r < 4; ++r)
          o[df][r] *= al[r];
      // No __syncthreads: P is strictly per-wave; the compiler's lgkmcnt wait on
      // the LDS dependency (same-address alias exists per-lane) orders write->read.
      bf16x8 pa0 = *reinterpret_cast<const bf16x8*>(&P[w][lr][lh * 8]);
      bf16x8 pa1 = *reinterpret_cast<const bf16x8*>(&P[w][lr][32 + lh * 8]);
#pragma unroll
      for (int df = 0; df < 4; ++df) {
        const bf16* vp = vb + (size_t)(df * 16 + lr) * Tt + kv0 + lh * 8;
        bf16x8 v0 = *reinterpret_cast<const bf16x8*>(vp);
        bf16x8 v1 = *reinterpret_cast<const bf16x8*>(vp + 32);
        o[df] = mfma16(pa0, v0, o[df]);
        o[df] = mfma16(pa1, v1, o[df]);
      }
    }

#pragma unroll
    for (int df = 0; df < 4; ++df) {
#pragma unroll
      for (int r = 0; r < 4; ++r) {
        int qrow = q0 + lh * 4 + r;
        float v = o[df][r] / lrow[r];
        Y[((size_t)b * Tt + qrow) * Ee + h * HDd + df * 16 + lr] = (bf16)v;
      }
    }
  }
}

extern "C" void kernel_launch(void* const* d_in, const int* in_sizes, int n_in,
                              void* d_out, int out_size, void* d_ws, size_t ws_size,
                              hipStream_t stream) {
  const float* x = (const float*)d_in[0];
  const float* w_attn = (const float*)d_in[1];
  const float* b_attn = (const float*)d_in[2];
  const float* w_proj = (const float*)d_in[3];
  const float* b_proj = (const float*)d_in[4];

  char* ws = (char*)d_ws;
  bf16* xbf = (bf16*)ws;                        // 16,777,216 B (later reused as Y)
  bf16* wat = (bf16*)(ws + 16777216);           //  6,291,456 B  w_attn^T bf16
  bf16* wpt = (bf16*)(ws + 23068672);           //  2,097,152 B  w_proj^T bf16
  bf16* vt  = (bf16*)(ws + 25165824);           // 16,777,216 B  V^T
  bf16* q   = (bf16*)d_out;                     // scratch in d_out (16.8 MB)
  bf16* k   = q + (size_t)M1 * Ee;              // scratch in d_out (16.8 MB)
  bf16* y   = xbf;                              // alias: x_bf16 dead after GEMM1

  // 1) casts / transposes
  k_cast<<<dim3((M1 * Ee / 4 + 255) / 256), dim3(256), 0, stream>>>(x, xbf, M1 * Ee / 4);
  k_transpose_cast<<<dim3(N1 / 32, K1 / 32), dim3(256), 0, stream>>>(w_attn, wat, K1, N1);
  k_transpose_cast<<<dim3(Ee / 32, Ee / 32), dim3(256), 0, stream>>>(w_proj, wpt, Ee, Ee);

  // 2) QKV GEMM (scatter epilogue)
  k_gemm_tn<1><<<dim3(N1 / 128, M1 / 128), dim3(256), 0, stream>>>(
      xbf, wat, b_attn, nullptr, q, k, vt, M1, N1, K1);

  // 3) flash attention (pair-balanced: 64 bh x 16 pairs)
  k_attn<<<dim3(Bb * Hh * 16), dim3(256), 0, stream>>>(q, k, vt, y);

  // 4) output projection (fp32 out)
  k_gemm_tn<0><<<dim3(Ee / 128, M1 / 128), dim3(256), 0, stream>>>(
      y, wpt, b_proj, (float*)d_out, nullptr, nullptr, nullptr, M1, Ee, K1);
}

// Round 13
// 328.886 us; speedup vs baseline: 2.0420x; 1.3721x over previous
//
#include <hip/hip_runtime.h>
#include <cstdint>
#include <cstddef>

typedef __bf16 bf16;
typedef __bf16 bf16x8 __attribute__((ext_vector_type(8)));
typedef __bf16 bf16x4 __attribute__((ext_vector_type(4)));
typedef float  f32x4  __attribute__((ext_vector_type(4)));

static constexpr int Bb = 4, Tt = 2048, Ee = 1024, Hh = 16, HDd = 64;
static constexpr int M1 = Bb * Tt;   // 8192
static constexpr int N1 = 3 * Ee;    // 3072
static constexpr int K1 = Ee;        // 1024

__device__ __forceinline__ f32x4 mfma16(bf16x8 a, bf16x8 b, f32x4 c) {
  return __builtin_amdgcn_mfma_f32_16x16x32_bf16(a, b, c, 0, 0, 0);
}

__device__ __forceinline__ void gl_lds16(bf16* lds, const bf16* g) {
  __builtin_amdgcn_global_load_lds(
      (const __attribute__((address_space(1))) void*)g,
      (__attribute__((address_space(3))) void*)lds, 16, 0, 0);
}

// ---------- cast fp32 -> bf16 (x4 vectorized) ----------
__global__ void k_cast(const float* __restrict__ in, bf16* __restrict__ out, int n4) {
  int i = blockIdx.x * blockDim.x + threadIdx.x;
  if (i >= n4) return;
  float4 v = reinterpret_cast<const float4*>(in)[i];
  bf16x4 o = { (bf16)v.x, (bf16)v.y, (bf16)v.z, (bf16)v.w };
  reinterpret_cast<bf16x4*>(out)[i] = o;
}

// ---------- transpose + cast: in[R][C] f32 -> out[C][R] bf16 ----------
__global__ void k_transpose_cast(const float* __restrict__ in, bf16* __restrict__ out,
                                 int R, int C) {
  __shared__ bf16 tile[32][33];
  int c0 = blockIdx.x * 32, r0 = blockIdx.y * 32;
  int tx = threadIdx.x & 31, ty = threadIdx.x >> 5;  // 256 thr: ty 0..7
#pragma unroll
  for (int i = 0; i < 32; i += 8)
    tile[ty + i][tx] = (bf16)in[(size_t)(r0 + ty + i) * C + c0 + tx];
  __syncthreads();
#pragma unroll
  for (int i = 0; i < 32; i += 8)
    out[(size_t)(c0 + ty + i) * R + r0 + tx] = tile[tx][ty + i];
}

// ---------- TN GEMM: C[M][N] = A[M][K] * Bt[N][K]^T  (+bias) ----------
// EPI 0: fp32 out[M][N] = acc + bias
// EPI 1: qkv scatter: q (scaled 1/8), k as [BH][T][64], v transposed [BH][64][T]
template <int EPI>
__global__ __launch_bounds__(256, 2)
void k_gemm_tn(const bf16* __restrict__ A, const bf16* __restrict__ Bt,
               const float* __restrict__ bias, float* __restrict__ outf,
               bf16* __restrict__ qo, bf16* __restrict__ ko, bf16* __restrict__ vto,
               int M, int N, int K) {
  __shared__ bf16 As[128 * 32];
  __shared__ bf16 Bs[128 * 32];
  const int n0 = blockIdx.x * 128;
  const int m0 = blockIdx.y * 128;
  const int w = threadIdx.x >> 6, lane = threadIdx.x & 63;
  const int wr = w >> 1, wc = w & 1;
  const int lr = lane & 15, lh = lane >> 4;

  // staging source: chunk of 16 rows; lane -> row lane/4, k-offset (lane&3)*8
  const int srow = lane >> 2;
  const int skk = (lane & 3) * 8;

  const bf16* gA0 = A + (size_t)(m0 + 32 * w + srow) * K + skk;
  const bf16* gA1 = A + (size_t)(m0 + 32 * w + 16 + srow) * K + skk;
  const bf16* gB0 = Bt + (size_t)(n0 + 32 * w + srow) * K + skk;
  const bf16* gB1 = Bt + (size_t)(n0 + 32 * w + 16 + srow) * K + skk;
  bf16* lA0 = As + (2 * w) * 512;
  bf16* lA1 = As + (2 * w + 1) * 512;
  bf16* lB0 = Bs + (2 * w) * 512;
  bf16* lB1 = Bs + (2 * w + 1) * 512;

  f32x4 acc[4][4] = {};

  for (int k0 = 0; k0 < K; k0 += 32) {
    gl_lds16(lA0, gA0 + k0);
    gl_lds16(lA1, gA1 + k0);
    gl_lds16(lB0, gB0 + k0);
    gl_lds16(lB1, gB1 + k0);
    __syncthreads();
    bf16x8 af[4], bfr[4];
#pragma unroll
    for (int m = 0; m < 4; ++m)
      af[m] = *reinterpret_cast<const bf16x8*>(As + (wr * 64 + m * 16 + lr) * 32 + lh * 8);
#pragma unroll
    for (int n = 0; n < 4; ++n)
      bfr[n] = *reinterpret_cast<const bf16x8*>(Bs + (wc * 64 + n * 16 + lr) * 32 + lh * 8);
#pragma unroll
    for (int m = 0; m < 4; ++m)
#pragma unroll
      for (int n = 0; n < 4; ++n)
        acc[m][n] = mfma16(af[m], bfr[n], acc[m][n]);
    __syncthreads();
  }

#pragma unroll
  for (int mf = 0; mf < 4; ++mf) {
#pragma unroll
    for (int nf = 0; nf < 4; ++nf) {
      int gn = n0 + wc * 64 + nf * 16 + lr;
      float bv = bias[gn];
#pragma unroll
      for (int r = 0; r < 4; ++r) {
        int gm = m0 + wr * 64 + mf * 16 + lh * 4 + r;
        float v = acc[mf][nf][r] + bv;
        if (EPI == 0) {
          outf[(size_t)gm * N + gn] = v;
        } else {
          int b = gm >> 11, t = gm & (Tt - 1);
          int sec = gn >> 10, rem = gn & (Ee - 1);
          int h = rem >> 6, d = rem & 63;
          size_t bh = (size_t)(b * Hh + h);
          if (sec == 0)
            qo[(bh * Tt + t) * HDd + d] = (bf16)(v * 0.125f);  // fold 1/sqrt(64)
          else if (sec == 1)
            ko[(bh * Tt + t) * HDd + d] = (bf16)v;
          else
            vto[(bh * HDd + d) * Tt + t] = (bf16)v;
        }
      }
    }
  }
}

// ---------- flash attention: Q[BH][T][64] x K[BH][T][64] -> causal softmax -> *Vt[BH][64][T] ----------
// Pair-balanced (33 KV-tiles per block), XCD-remapped, block-cooperative LDS
// staging of K/V (global_load_lds, 4x traffic cut vs per-wave global loads).
// LDS K/V tiles are XOR-swizzled (T2): linear LDS dest + inverse-swizzled
// global source; ds_read_b128 applies the same XOR -> conflict-free.
__global__ __launch_bounds__(256, 2)
void k_attn(const bf16* __restrict__ Q, const bf16* __restrict__ Kg,
            const bf16* __restrict__ Vt, bf16* __restrict__ Y) {
  __shared__ bf16 Kl[4096];      // [64 kv][64 d] swizzled, 8 KB
  __shared__ bf16 Vl[4096];      // [64 d][64 kv] swizzled, 8 KB
  __shared__ bf16 P[4][16][72];  // per-wave P tile, row stride 144B
  const int blk = blockIdx.x;
  // bijective XCD-contiguous remap (1024 blocks, 8 XCDs, XCD = blk%8):
  const int work = ((blk & 7) << 7) + (blk >> 3);
  const int bh = work >> 4, pr = work & 15;
  const int w = threadIdx.x >> 6, lane = threadIdx.x & 63;
  const int lr = lane & 15, lh = lane >> 4;

  const bf16* kb = Kg + (size_t)bh * Tt * HDd;
  const bf16* vb = Vt + (size_t)bh * HDd * Tt;
  const int b = bh >> 4, h = bh & 15;

  // --- staging geometry: 16 KB = 16 wave-instrs of 1KB; wave w does 2 K + 2 V.
  // lane L covers LDS row (16w + 8j + L/8), element-cols (L&7)*8 .. +7 with the
  // swizzle col ^= (row&7)*8 folded into the GLOBAL source address (rule #21).
  const int srow = lane >> 3;                 // 0..7
  const int scolswz = ((lane & 7) * 8) ^ (srow * 8);
  const bf16* gK0 = kb + (size_t)(16 * w + srow) * HDd + scolswz;       // + kv0*64
  const bf16* gK1 = kb + (size_t)(16 * w + 8 + srow) * HDd + scolswz;
  const bf16* gV0 = vb + (size_t)(16 * w + srow) * Tt + scolswz;        // + kv0
  const bf16* gV1 = vb + (size_t)(16 * w + 8 + srow) * Tt + scolswz;
  bf16* lK0 = Kl + (2 * w) * 512;
  bf16* lK1 = Kl + (2 * w + 1) * 512;
  bf16* lV0 = Vl + (2 * w) * 512;
  bf16* lV1 = Vl + (2 * w + 1) * 512;

  // --- read-side swizzled fragment offsets (elements). For frag row fr=f*16+lr
  // (both K and V reads), fr&7 == lr&7, so the XOR term is lane-constant:
  const int koff0 = lr * 64 + ((lh * 8) ^ ((lr & 7) * 8));        // k-dim 0..31
  const int koff1 = lr * 64 + (((32 + lh * 8)) ^ ((lr & 7) * 8)); // k-dim 32..63

  for (int ph = 0; ph < 2; ++ph) {
    const int qb = ph ? pr : (31 - pr);  // hi first: lo's K/V tiles then L2-warm
    const int q0 = qb * 64 + w * 16;

    const bf16* qp = Q + ((size_t)bh * Tt + q0 + lr) * HDd + lh * 8;
    bf16x8 aq0 = *reinterpret_cast<const bf16x8*>(qp);
    bf16x8 aq1 = *reinterpret_cast<const bf16x8*>(qp + 32);

    float mrow[4], lrow[4];
    f32x4 o[4] = {};
#pragma unroll
    for (int r = 0; r < 4; ++r) { mrow[r] = -INFINITY; lrow[r] = 0.f; }

    for (int t = 0; t <= qb; ++t) {
      const int kv0 = t * 64;
      __syncthreads();  // all waves done reading previous K/V tile
      gl_lds16(lK0, gK0 + (size_t)kv0 * HDd);
      gl_lds16(lK1, gK1 + (size_t)kv0 * HDd);
      gl_lds16(lV0, gV0 + kv0);
      gl_lds16(lV1, gV1 + kv0);
      __syncthreads();  // staging complete (vmcnt drained by barrier semantics)

      f32x4 s[4] = {};
#pragma unroll
      for (int fc = 0; fc < 4; ++fc) {
        bf16x8 b0 = *reinterpret_cast<const bf16x8*>(Kl + koff0 + fc * 1024);
        bf16x8 b1 = *reinterpret_cast<const bf16x8*>(Kl + koff1 + fc * 1024);
        s[fc] = mfma16(aq0, b0, s[fc]);
        s[fc] = mfma16(aq1, b1, s[fc]);
      }
      if (t == qb) {  // diagonal tile: causal mask
#pragma unroll
        for (int fc = 0; fc < 4; ++fc)
#pragma unroll
          for (int r = 0; r < 4; ++r)
            if (kv0 + fc * 16 + lr > q0 + lh * 4 + r) s[fc][r] = -INFINITY;
      }
      float pm[4], al[4], ps[4];
#pragma unroll
      for (int r = 0; r < 4; ++r)
        pm[r] = fmaxf(fmaxf(s[0][r], s[1][r]), fmaxf(s[2][r], s[3][r]));
#pragma unroll
      for (int msk = 1; msk < 16; msk <<= 1)
#pragma unroll
        for (int r = 0; r < 4; ++r)
          pm[r] = fmaxf(pm[r], __shfl_xor(pm[r], msk));
#pragma unroll
      for (int r = 0; r < 4; ++r) {
        float nm = fmaxf(mrow[r], pm[r]);
        al[r] = __expf(mrow[r] - nm);
        mrow[r] = nm;
        ps[r] = 0.f;
      }
#pragma unroll
      for (int fc = 0; fc < 4; ++fc) {
#pragma unroll
        for (int r = 0; r < 4; ++r) {
          float p = __expf(s[fc][r] - mrow[r]);
          ps[r] += p;
          P[w][lh * 4 + r][fc * 16 + lr] = (bf16)p;
        }
      }
#pragma unroll
      for (int msk = 1; msk < 16; msk <<= 1)
#pragma unroll
        for (int r = 0; r < 4; ++r)
          ps[r] += __shfl_xor(ps[r], msk);
#pragma unroll
      for (int r = 0; r < 4; ++r)
        lrow[r] = lrow[r] * al[r] + ps[r];
#pragma unroll
      for (int df = 0; df < 4; ++df)
#pragma unroll
        for (int r = 0; r < 4; ++r)
          o[df][r] *= al[r];
      // P is per-wave: write->read ordered by the wave's own lgkmcnt waits.
      bf16x8 pa0 = *reinterpret_cast<const bf16x8*>(&P[w][lr][lh * 8]);
      bf16x8 pa1 = *reinterpret_cast<const bf16x8*>(&P[w][lr][32 + lh * 8]);
#pragma unroll
      for (int df = 0; df < 4; ++df) {
        bf16x8 v0 = *reinterpret_cast<const bf16x8*>(Vl + koff0 + df * 1024);
        bf16x8 v1 = *reinterpret_cast<const bf16x8*>(Vl + koff1 + df * 1024);
        o[df] = mfma16(pa0, v0, o[df]);
        o[df] = mfma16(pa1, v1, o[df]);
      }
    }

#pragma unroll
    for (int df = 0; df < 4; ++df) {
#pragma unroll
      for (int r = 0; r < 4; ++r) {
        int qrow = q0 + lh * 4 + r;
        float v = o[df][r] / lrow[r];
        Y[((size_t)b * Tt + qrow) * Ee + h * HDd + df * 16 + lr] = (bf16)v;
      }
    }
  }
}

extern "C" void kernel_launch(void* const* d_in, const int* in_sizes, int n_in,
                              void* d_out, int out_size, void* d_ws, size_t ws_size,
                              hipStream_t stream) {
  const float* x = (const float*)d_in[0];
  const float* w_attn = (const float*)d_in[1];
  const float* b_attn = (const float*)d_in[2];
  const float* w_proj = (const float*)d_in[3];
  const float* b_proj = (const float*)d_in[4];

  char* ws = (char*)d_ws;
  bf16* xbf = (bf16*)ws;                        // 16,777,216 B (later reused as Y)
  bf16* wat = (bf16*)(ws + 16777216);           //  6,291,456 B  w_attn^T bf16
  bf16* wpt = (bf16*)(ws + 23068672);           //  2,097,152 B  w_proj^T bf16
  bf16* vt  = (bf16*)(ws + 25165824);           // 16,777,216 B  V^T
  bf16* q   = (bf16*)d_out;                     // scratch in d_out (16.8 MB)
  bf16* k   = q + (size_t)M1 * Ee;              // scratch in d_out (16.8 MB)
  bf16* y   = xbf;                              // alias: x_bf16 dead after GEMM1

  // 1) casts / transposes
  k_cast<<<dim3((M1 * Ee / 4 + 255) / 256), dim3(256), 0, stream>>>(x, xbf, M1 * Ee / 4);
  k_transpose_cast<<<dim3(N1 / 32, K1 / 32), dim3(256), 0, stream>>>(w_attn, wat, K1, N1);
  k_transpose_cast<<<dim3(Ee / 32, Ee / 32), dim3(256), 0, stream>>>(w_proj, wpt, Ee, Ee);

  // 2) QKV GEMM (scatter epilogue)
  k_gemm_tn<1><<<dim3(N1 / 128, M1 / 128), dim3(256), 0, stream>>>(
      xbf, wat, b_attn, nullptr, q, k, vt, M1, N1, K1);

  // 3) flash attention (pair-balanced: 64 bh x 16 pairs, LDS-staged K/V)
  k_attn<<<dim3(Bb * Hh * 16), dim3(256), 0, stream>>>(q, k, vt, y);

  // 4) output projection (fp32 out)
  k_gemm_tn<0><<<dim3(Ee / 128, M1 / 128), dim3(256), 0, stream>>>(
      y, wpt, b_proj, (float*)d_out, nullptr, nullptr, nullptr, M1, Ee, K1);
}